// Round 4
// baseline (812.164 us; speedup 1.0000x reference)
//
#include <hip/hip_runtime.h>
#include <hip/hip_bf16.h>

// B=2, DIM=32, CV=HDIM=96, H=W=512, FOLD=8 -> 128 tiles of 64x64, S=4 (P=2), NCLS=16.
// R4: pass2/pass3 software-pipelined (single-buffered register prefetch of next
// chunk's global loads, issued right after consume -> in flight across the
// combine/score/MFMA sync phases). k_centers folded into pass2 preamble
// (scratch overlaid on s_pfT; serial deterministic gconst/norm0). fin1 preamble
// in pass3 made deterministic. 4 kernels total.

// ---- ws layout (float offsets) ----
#define OFF_POOLX   0          // [128][32][4]
#define OFF_POOLS   16384      // [128][31][4]
#define OFF_CENPF0  32256      // [128][96][4]
#define OFF_NUM1    114688     // [128][96][4]  (zeroed, atomics)
#define OFF_DEN1    163840     // [128][4]      (zeroed, atomics)
#define OFF_OUTNUM  214016     // [128][96][4]  (zeroed, atomics)
#define OFF_OUTDEN  263168     // [128][4]      (zeroed, atomics)
#define OFF_LABELS  263680     // [128][4][16]  (zeroed, atomics)
#define OFF_G       271872     // [128][4096][4] f32 interleaved (px-major, s-minor)
#define ZERO_BASE   OFF_NUM1
#define ZERO_LEN    157184     // floats: NUM1..LABELS end

// ---- d_out layout (float elements) ----
#define OUT_CF 0        // center_feat [2][256][96]
#define OUT_LB 49152    // labels      [2][16][256]
#define OUT_SP 57344    // spix_map    [2][512][512]

#define PL 262144       // plane size (floats)

typedef float f32x4 __attribute__((ext_vector_type(4)));
typedef short bf16x8 __attribute__((ext_vector_type(8)));
typedef unsigned short u16x4 __attribute__((ext_vector_type(4)));

__device__ __forceinline__ unsigned short f2bf(float f) {
  return (unsigned short)(__float_as_uint(f) >> 16);   // truncate; tolerant paths only
}

// K1: block per (plane 0..317, f1 band 0..7): reads 64 rows x 512 cols (128 KB),
// writes 8 tiles x 4 quadrant means. Known-good ~118-120us reader.
// Also zero-inits the atomic ws regions (replaces hipMemsetAsync dispatch).
__global__ __launch_bounds__(256) void k_pool(const float* __restrict__ x,
    const float* __restrict__ feat, const float* __restrict__ sdf,
    float* __restrict__ ws) {
  int plane = blockIdx.x, f1 = blockIdx.y, tid = threadIdx.x;
  {
    int lb = blockIdx.y * gridDim.x + blockIdx.x;
    if (tid < 64) {
      int zi = lb * 64 + tid;
      if (zi < ZERO_LEN) ws[ZERO_BASE + zi] = 0.f;
    }
  }
  int b = plane / 159, ch = plane % 159;
  const float* src; int c, C, cls;
  if (ch < 32)      { src = x;    C = 32; c = ch;      cls = 0; }
  else if (ch < 63) { src = sdf;  C = 31; c = ch - 32; cls = 1; }
  else              { src = feat; C = 96; c = ch - 63; cls = 2; }
  const float* base = src + ((size_t)(b*C + c)*512 + f1*64)*512;
  int half = tid >> 7, col4 = tid & 127;
  const float* p0 = base + (size_t)half*512 + (size_t)col4*4;  // rows y=2i+half
  f32x4 v[16];
  float acc0 = 0.f, acc1 = 0.f;    // qy=0 / qy=1
  #pragma unroll
  for (int i = 0; i < 16; ++i)
    v[i] = *reinterpret_cast<const f32x4*>(p0 + (size_t)i*1024);
  #pragma unroll
  for (int i = 0; i < 16; ++i) { f32x4 t = v[i]; acc0 += t[0] + t[1] + t[2] + t[3]; }
  #pragma unroll
  for (int i = 0; i < 16; ++i)
    v[i] = *reinterpret_cast<const f32x4*>(p0 + (size_t)(16 + i)*1024);
  #pragma unroll
  for (int i = 0; i < 16; ++i) { f32x4 t = v[i]; acc1 += t[0] + t[1] + t[2] + t[3]; }
  acc0 += __shfl_xor(acc0, 1, 64); acc0 += __shfl_xor(acc0, 2, 64); acc0 += __shfl_xor(acc0, 4, 64);
  acc1 += __shfl_xor(acc1, 1, 64); acc1 += __shfl_xor(acc1, 2, 64); acc1 += __shfl_xor(acc1, 4, 64);
  __shared__ float part[32][2];
  int lane = tid & 63;
  if ((lane & 7) == 0) {
    int f2 = col4 >> 4, qx = (col4 >> 3) & 1;
    part[(f2*2 + qx)*2 + 0][half] = acc0;
    part[(f2*2 + qx)*2 + 1][half] = acc1;
  }
  __syncthreads();
  if (tid < 32) {
    float v2 = (part[tid][0] + part[tid][1]) * (1.f/1024.f);
    int f2 = tid >> 2, qx = (tid >> 1) & 1, qy = tid & 1;
    int tile = b*64 + f1*8 + f2, s = qy*2 + qx;
    float* dst;
    if (cls == 0)      dst = ws + OFF_POOLX  + (tile*32 + c)*4;
    else if (cls == 1) dst = ws + OFF_POOLS  + (tile*31 + c)*4;
    else               dst = ws + OFF_CENPF0 + (tile*96 + c)*4;
    dst[s] = v2;
  }
}

// K3: SSN iter0. 4 WGs/tile x 1024 px, 4 chunks of 256 px.
// Centers (cen_df/cen_sf -> u_df/u_sf, gconst, norm0) computed per-block in a
// preamble (scratch overlaid on s_pfT). Main loop: single-buffered register
// prefetch of next chunk's x/sdf/feat float4 loads.
__global__ __launch_bounds__(256, 2) void k_pass2(const float* __restrict__ x,
    const float* __restrict__ feat, const float* __restrict__ sdf,
    const float* __restrict__ Wf, const float* __restrict__ bfv,
    const float* __restrict__ Wsdf, const float* __restrict__ bsdf,
    float* __restrict__ ws) {
  int wg = blockIdx.x, tile = wg >> 2, seg = wg & 3, tid = threadIdx.x;
  int b = tile >> 6, tl = tile & 63, f1 = tl >> 3, f2 = tl & 7;
  __shared__ float s_cpf0[384];
  __shared__ float s_udf[128];
  __shared__ float s_usf[124];
  __shared__ float s_gc[4], s_n0[4];
  __shared__ __align__(16) unsigned short s_pfT[96][264];  // [c][px] bf16
  __shared__ __align__(16) unsigned short s_aT[16][264];   // [n][px] bf16; rows 4..15 zero
  __shared__ __align__(16) float s_part[2][8][260];        // [pair][d0-3,p0-3][px]
  // ---- fused k_centers preamble; scratch overlays s_pfT storage ----
  float* scr  = reinterpret_cast<float*>(&s_pfT[0][0]);
  float* c_px = scr;          // [128]
  float* c_ps = scr + 128;    // [124]
  float* c_df = scr + 256;    // [384]
  float* c_sf = scr + 640;    // [384]
  for (int i = tid; i < 384; i += 256) s_cpf0[i] = ws[OFF_CENPF0 + tile*384 + i];
  if (tid < 128) c_px[tid] = ws[OFF_POOLX + tile*128 + tid];
  if (tid < 124) c_ps[tid] = ws[OFF_POOLS + tile*124 + tid];
  __syncthreads();
  for (int i = tid; i < 384; i += 256) {
    int c = i % 96, s = i / 96;
    float a = bfv[c];
    for (int k = 0; k < 32; ++k) a += Wf[c*32 + k] * c_px[k*4 + s];
    c_df[c*4 + s] = a;
    float a2 = bsdf[c];
    for (int k = 0; k < 31; ++k) a2 += Wsdf[c*31 + k] * c_ps[k*4 + s];
    c_sf[c*4 + s] = a2;
  }
  __syncthreads();
  if (tid < 128) {
    int s2 = tid >> 5, k = tid & 31;
    float u = 0.f;
    for (int c2 = 0; c2 < 96; ++c2) u += Wf[c2*32 + k] * c_df[c2*4 + s2];
    s_udf[tid] = u;
  } else if (tid < 252) {
    int t2 = tid - 128, s2 = t2 / 31, k = t2 % 31;
    float u = 0.f;
    for (int c2 = 0; c2 < 96; ++c2) u += Wsdf[c2*31 + k] * c_sf[c2*4 + s2];
    s_usf[t2] = u;
  } else {
    int s = tid - 252;           // deterministic serial gconst/norm0
    float g = 0.f, n = 0.f;
    for (int c = 0; c < 96; ++c) {
      float a = c_df[c*4 + s], a2 = c_sf[c*4 + s];
      g += 2.f*(bfv[c]*a + bsdf[c]*a2) - (a*a + a2*a2);
      float cp = s_cpf0[c*4 + s];
      n += cp*cp;
    }
    s_gc[s] = g; s_n0[s] = n;
  }
  for (int i = tid; i < 16*264; i += 256) (&s_aT[0][0])[i] = 0;
  __syncthreads();   // scratch region free; s_pfT usable from here
  int lane = tid & 63, wave = tid >> 6;
  int mrow = lane & 15, quad = lane >> 4;
  int q4 = lane * 4;
  f32x4 zero4 = {0.f, 0.f, 0.f, 0.f};
  f32x4 accC[6] = {zero4, zero4, zero4, zero4, zero4, zero4};
  float dden[4] = {0.f, 0.f, 0.f, 0.f};
  const float* xb = x   + (size_t)(b*32)*PL;
  const float* sb = sdf + (size_t)(b*31)*PL;
  const float* fb = feat+ (size_t)(b*96)*PL;
  // prefetch chunk 0
  f32x4 xv[8], sv[8], fv[24];
  {
    int pq = seg*1024 + q4;
    int goq = (f1*64 + (pq >> 6))*512 + f2*64 + (pq & 63);
    #pragma unroll
    for (int i = 0; i < 8; ++i)
      xv[i] = *reinterpret_cast<const f32x4*>(xb + (size_t)(wave + 4*i)*PL + goq);
    #pragma unroll
    for (int i = 0; i < 8; ++i)
      if (wave + 4*i < 31)
        sv[i] = *reinterpret_cast<const f32x4*>(sb + (size_t)(wave + 4*i)*PL + goq);
    #pragma unroll
    for (int i = 0; i < 24; ++i)
      fv[i] = *reinterpret_cast<const f32x4*>(fb + (size_t)(wave + 4*i)*PL + goq);
  }
  for (int chunk = 0; chunk < 4; ++chunk) {
    int pq1 = seg*1024 + (chunk+1)*256 + q4;
    int goq1 = (f1*64 + (pq1 >> 6))*512 + f2*64 + (pq1 & 63);
    f32x4 dpd[4] = {zero4, zero4, zero4, zero4};
    f32x4 dpp[4] = {zero4, zero4, zero4, zero4};
    // consume x, reissue next chunk into same regs (WAR keeps single buffer)
    #pragma unroll
    for (int i = 0; i < 8; ++i) {
      int ch = wave + 4*i;
      #pragma unroll
      for (int s = 0; s < 4; ++s) dpd[s] += xv[i] * s_udf[s*32 + ch];
    }
    if (chunk < 3) {
      #pragma unroll
      for (int i = 0; i < 8; ++i)
        xv[i] = *reinterpret_cast<const f32x4*>(xb + (size_t)(wave + 4*i)*PL + goq1);
    }
    // consume sdf, reissue
    #pragma unroll
    for (int i = 0; i < 8; ++i) {
      int ch = wave + 4*i;
      if (ch < 31) {
        #pragma unroll
        for (int s = 0; s < 4; ++s) dpd[s] += sv[i] * s_usf[s*31 + ch];
      }
    }
    if (chunk < 3) {
      #pragma unroll
      for (int i = 0; i < 8; ++i)
        if (wave + 4*i < 31)
          sv[i] = *reinterpret_cast<const f32x4*>(sb + (size_t)(wave + 4*i)*PL + goq1);
    }
    // consume feat (+ bf16 stage to LDS), reissue
    #pragma unroll
    for (int i = 0; i < 24; ++i) {
      int ch = wave + 4*i;
      u16x4 uu = { f2bf(fv[i][0]), f2bf(fv[i][1]), f2bf(fv[i][2]), f2bf(fv[i][3]) };
      *reinterpret_cast<u16x4*>(&s_pfT[ch][q4]) = uu;
      #pragma unroll
      for (int s = 0; s < 4; ++s) dpp[s] += fv[i] * s_cpf0[ch*4 + s];
    }
    if (chunk < 3) {
      #pragma unroll
      for (int i = 0; i < 24; ++i)
        fv[i] = *reinterpret_cast<const f32x4*>(fb + (size_t)(wave + 4*i)*PL + goq1);
    }
    // combine partials: waves 2,3 store; waves 0,1 add
    if (wave >= 2) {
      #pragma unroll
      for (int s = 0; s < 4; ++s) {
        *reinterpret_cast<f32x4*>(&s_part[wave-2][s][q4]) = dpd[s];
        *reinterpret_cast<f32x4*>(&s_part[wave-2][4+s][q4]) = dpp[s];
      }
    }
    __syncthreads();
    if (wave < 2) {
      #pragma unroll
      for (int s = 0; s < 4; ++s) {
        f32x4 t = *reinterpret_cast<f32x4*>(&s_part[wave][s][q4]);
        t += dpd[s];
        *reinterpret_cast<f32x4*>(&s_part[wave][s][q4]) = t;
        f32x4 t2 = *reinterpret_cast<f32x4*>(&s_part[wave][4+s][q4]);
        t2 += dpp[s];
        *reinterpret_cast<f32x4*>(&s_part[wave][4+s][q4]) = t2;
      }
    }
    __syncthreads();
    // score phase: px = tid
    float d0 = s_part[0][0][tid] + s_part[1][0][tid];
    float d1 = s_part[0][1][tid] + s_part[1][1][tid];
    float d2 = s_part[0][2][tid] + s_part[1][2][tid];
    float d3 = s_part[0][3][tid] + s_part[1][3][tid];
    float p0 = s_part[0][4][tid] + s_part[1][4][tid];
    float p1 = s_part[0][5][tid] + s_part[1][5][tid];
    float p2 = s_part[0][6][tid] + s_part[1][6][tid];
    float p3 = s_part[0][7][tid] + s_part[1][7][tid];
    float g0 = 2.f*d0 + s_gc[0], g1 = 2.f*d1 + s_gc[1];
    float g2 = 2.f*d2 + s_gc[2], g3 = 2.f*d3 + s_gc[3];
    int p = seg*1024 + chunk*256 + tid;
    {
      f32x4 gv = {g0, g1, g2, g3};
      *reinterpret_cast<f32x4*>(ws + OFF_G + ((size_t)tile << 14) + (size_t)p*4) = gv;
    }
    float sc0 = g0 + 2.f*p0 - s_n0[0];
    float sc1 = g1 + 2.f*p1 - s_n0[1];
    float sc2 = g2 + 2.f*p2 - s_n0[2];
    float sc3 = g3 + 2.f*p3 - s_n0[3];
    float m = fmaxf(fmaxf(sc0, sc1), fmaxf(sc2, sc3));
    float e0 = expf(sc0 - m), e1 = expf(sc1 - m), e2 = expf(sc2 - m), e3 = expf(sc3 - m);
    float inv = 1.f / (e0 + e1 + e2 + e3);
    float a0 = e0*inv, a1 = e1*inv, a2 = e2*inv, a3 = e3*inv;
    s_aT[0][tid] = f2bf(a0); s_aT[1][tid] = f2bf(a1);
    s_aT[2][tid] = f2bf(a2); s_aT[3][tid] = f2bf(a3);
    dden[0] += a0; dden[1] += a1; dden[2] += a2; dden[3] += a3;
    __syncthreads();
    #pragma unroll
    for (int kk = 0; kk < 2; ++kk) {
      int k0 = (wave*2 + kk)*32 + quad*8;
      bf16x8 bfrag = *reinterpret_cast<const bf16x8*>(&s_aT[mrow][k0]);
      #pragma unroll
      for (int mt = 0; mt < 6; ++mt) {
        bf16x8 afrag = *reinterpret_cast<const bf16x8*>(&s_pfT[mt*16 + mrow][k0]);
        accC[mt] = __builtin_amdgcn_mfma_f32_16x16x32_bf16(afrag, bfrag, accC[mt], 0, 0, 0);
      }
    }
    __syncthreads();
  }
  if (mrow < 4) {     // C/D: col=lane&15 (=s), row=quad*4+reg (=c within tile)
    #pragma unroll
    for (int mt = 0; mt < 6; ++mt)
      #pragma unroll
      for (int r = 0; r < 4; ++r) {
        int c = mt*16 + quad*4 + r;
        atomicAdd(&ws[OFF_NUM1 + (tile*96 + c)*4 + mrow], accC[mt][r]);
      }
  }
  for (int m2 = 1; m2 < 64; m2 <<= 1) {
    dden[0] += __shfl_xor(dden[0], m2, 64); dden[1] += __shfl_xor(dden[1], m2, 64);
    dden[2] += __shfl_xor(dden[2], m2, 64); dden[3] += __shfl_xor(dden[3], m2, 64);
  }
  if (lane == 0) {
    atomicAdd(&ws[OFF_DEN1 + tile*4 + 0], dden[0]);
    atomicAdd(&ws[OFF_DEN1 + tile*4 + 1], dden[1]);
    atomicAdd(&ws[OFF_DEN1 + tile*4 + 2], dden[2]);
    atomicAdd(&ws[OFF_DEN1 + tile*4 + 3], dden[3]);
  }
}

// K5: SSN iter1. fin1 fused (deterministic). Register prefetch of feat + g + gt.
__global__ __launch_bounds__(256, 2) void k_pass3(const float* __restrict__ feat,
    const int* __restrict__ gt, float* __restrict__ ws, float* __restrict__ out) {
  int wg = blockIdx.x, tile = wg >> 2, seg = wg & 3, tid = threadIdx.x;
  int b = tile >> 6, tl = tile & 63, f1 = tl >> 3, f2 = tl & 7;
  __shared__ float s_cpf1[384];
  __shared__ float s_n1[4];
  __shared__ __align__(16) unsigned short s_pfT[96][264];
  __shared__ __align__(16) unsigned short s_aT[16][264];
  __shared__ __align__(16) float s_part[2][4][260];
  __shared__ float s_hist[64];
  if (tid < 64) s_hist[tid] = 0.f;
  for (int i = tid; i < 16*264; i += 256) (&s_aT[0][0])[i] = 0;
  // fused fin1: cen_pf1 = NUM1/(DEN1+eps); then deterministic norm1
  for (int i = tid; i < 384; i += 256) {
    float den = ws[OFF_DEN1 + tile*4 + (i & 3)];
    s_cpf1[i] = ws[OFF_NUM1 + tile*384 + i] / (den + 1e-16f);
  }
  __syncthreads();
  if (tid < 4) {
    float n = 0.f;
    for (int c = 0; c < 96; ++c) { float v = s_cpf1[c*4 + tid]; n += v*v; }
    s_n1[tid] = n;
  }
  __syncthreads();
  int lane = tid & 63, wave = tid >> 6;
  int mrow = lane & 15, quad = lane >> 4;
  int q4 = lane * 4;
  f32x4 zero4 = {0.f, 0.f, 0.f, 0.f};
  f32x4 accC[6] = {zero4, zero4, zero4, zero4, zero4, zero4};
  float oden[4] = {0.f, 0.f, 0.f, 0.f};
  const float* fb = feat + (size_t)(b*96)*PL;
  // prefetch chunk 0
  f32x4 fv[24]; f32x4 gfut; int gtfut;
  {
    int pq = seg*1024 + q4;
    int goq = (f1*64 + (pq >> 6))*512 + f2*64 + (pq & 63);
    #pragma unroll
    for (int i = 0; i < 24; ++i)
      fv[i] = *reinterpret_cast<const f32x4*>(fb + (size_t)(wave + 4*i)*PL + goq);
    int p0i = seg*1024 + tid;
    gfut = *reinterpret_cast<const f32x4*>(ws + OFF_G + ((size_t)tile << 14) + (size_t)p0i*4);
    gtfut = gt[b*262144 + (f1*64 + (p0i >> 6))*512 + f2*64 + (p0i & 63)];
  }
  for (int chunk = 0; chunk < 4; ++chunk) {
    int pq1 = seg*1024 + (chunk+1)*256 + q4;
    int goq1 = (f1*64 + (pq1 >> 6))*512 + f2*64 + (pq1 & 63);
    f32x4 dpp[4] = {zero4, zero4, zero4, zero4};
    f32x4 gcur = gfut; int gtcur = gtfut;
    // consume feat, reissue
    #pragma unroll
    for (int i = 0; i < 24; ++i) {
      int ch = wave + 4*i;
      u16x4 uu = { f2bf(fv[i][0]), f2bf(fv[i][1]), f2bf(fv[i][2]), f2bf(fv[i][3]) };
      *reinterpret_cast<u16x4*>(&s_pfT[ch][q4]) = uu;
      #pragma unroll
      for (int s = 0; s < 4; ++s) dpp[s] += fv[i] * s_cpf1[ch*4 + s];
    }
    if (chunk < 3) {
      #pragma unroll
      for (int i = 0; i < 24; ++i)
        fv[i] = *reinterpret_cast<const f32x4*>(fb + (size_t)(wave + 4*i)*PL + goq1);
      int p1i = seg*1024 + (chunk+1)*256 + tid;
      gfut = *reinterpret_cast<const f32x4*>(ws + OFF_G + ((size_t)tile << 14) + (size_t)p1i*4);
      gtfut = gt[b*262144 + (f1*64 + (p1i >> 6))*512 + f2*64 + (p1i & 63)];
    }
    if (wave >= 2) {
      #pragma unroll
      for (int s = 0; s < 4; ++s)
        *reinterpret_cast<f32x4*>(&s_part[wave-2][s][q4]) = dpp[s];
    }
    __syncthreads();
    if (wave < 2) {
      #pragma unroll
      for (int s = 0; s < 4; ++s) {
        f32x4 t = *reinterpret_cast<f32x4*>(&s_part[wave][s][q4]);
        t += dpp[s];
        *reinterpret_cast<f32x4*>(&s_part[wave][s][q4]) = t;
      }
    }
    __syncthreads();
    // score phase: px = tid
    int p = seg*1024 + chunk*256 + tid;
    int go = (f1*64 + (p >> 6))*512 + f2*64 + (p & 63);
    float p0 = s_part[0][0][tid] + s_part[1][0][tid];
    float p1 = s_part[0][1][tid] + s_part[1][1][tid];
    float p2 = s_part[0][2][tid] + s_part[1][2][tid];
    float p3 = s_part[0][3][tid] + s_part[1][3][tid];
    float sc0 = gcur[0] + 2.f*p0 - s_n1[0];
    float sc1 = gcur[1] + 2.f*p1 - s_n1[1];
    float sc2 = gcur[2] + 2.f*p2 - s_n1[2];
    float sc3 = gcur[3] + 2.f*p3 - s_n1[3];
    int ss = 0; float best = sc0;
    if (sc1 > best) { best = sc1; ss = 1; }
    if (sc2 > best) { best = sc2; ss = 2; }
    if (sc3 > best) { best = sc3; ss = 3; }
    float se = expf(sc0-best) + expf(sc1-best) + expf(sc2-best) + expf(sc3-best);
    float sim = 1.f / se;
    unsigned short sb = f2bf(sim);
    s_aT[0][tid] = (ss == 0) ? sb : (unsigned short)0;
    s_aT[1][tid] = (ss == 1) ? sb : (unsigned short)0;
    s_aT[2][tid] = (ss == 2) ? sb : (unsigned short)0;
    s_aT[3][tid] = (ss == 3) ? sb : (unsigned short)0;
    oden[ss] += sim;
    atomicAdd(&s_hist[ss*16 + gtcur], 1.f);
    out[OUT_SP + b*262144 + go] = (float)(tl*4 + ss);
    __syncthreads();
    #pragma unroll
    for (int kk = 0; kk < 2; ++kk) {
      int k0 = (wave*2 + kk)*32 + quad*8;
      bf16x8 bfrag = *reinterpret_cast<const bf16x8*>(&s_aT[mrow][k0]);
      #pragma unroll
      for (int mt = 0; mt < 6; ++mt) {
        bf16x8 afrag = *reinterpret_cast<const bf16x8*>(&s_pfT[mt*16 + mrow][k0]);
        accC[mt] = __builtin_amdgcn_mfma_f32_16x16x32_bf16(afrag, bfrag, accC[mt], 0, 0, 0);
      }
    }
    __syncthreads();
  }
  if (mrow < 4) {
    #pragma unroll
    for (int mt = 0; mt < 6; ++mt)
      #pragma unroll
      for (int r = 0; r < 4; ++r) {
        int c = mt*16 + quad*4 + r;
        atomicAdd(&ws[OFF_OUTNUM + (tile*96 + c)*4 + mrow], accC[mt][r]);
      }
  }
  for (int m2 = 1; m2 < 64; m2 <<= 1) {
    oden[0] += __shfl_xor(oden[0], m2, 64); oden[1] += __shfl_xor(oden[1], m2, 64);
    oden[2] += __shfl_xor(oden[2], m2, 64); oden[3] += __shfl_xor(oden[3], m2, 64);
  }
  if (lane == 0) {
    atomicAdd(&ws[OFF_OUTDEN + tile*4 + 0], oden[0]);
    atomicAdd(&ws[OFF_OUTDEN + tile*4 + 1], oden[1]);
    atomicAdd(&ws[OFF_OUTDEN + tile*4 + 2], oden[2]);
    atomicAdd(&ws[OFF_OUTDEN + tile*4 + 3], oden[3]);
  }
  if (tid < 64) atomicAdd(&ws[OFF_LABELS + tile*64 + tid], s_hist[tid]);
}

// K6: epilogue -> center_feat and labels
__global__ __launch_bounds__(384) void k_out(const float* __restrict__ ws,
                                             float* __restrict__ out) {
  int tile = blockIdx.x, tid = threadIdx.x;
  int b = tile >> 6, tl = tile & 63;
  int c = tid % 96, s = tid / 96;
  float od = ws[OFF_OUTDEN + tile*4 + s];
  float v = (ws[OFF_OUTNUM + (tile*96 + c)*4 + s] + ws[OFF_CENPF0 + (tile*96 + c)*4 + s]) / (od + 1.f);
  out[OUT_CF + (size_t)(b*256 + tl*4 + s)*96 + c] = v;
  if (tid < 64) {
    int s2 = tid >> 4, cls = tid & 15;
    float cnt = ws[OFF_LABELS + tile*64 + tid];
    out[OUT_LB + (b*16 + cls)*256 + tl*4 + s2] = cnt;
  }
}

extern "C" void kernel_launch(void* const* d_in, const int* in_sizes, int n_in,
                              void* d_out, int out_size, void* d_ws, size_t ws_size,
                              hipStream_t stream) {
  const float* x    = (const float*)d_in[0];
  const float* feat = (const float*)d_in[1];
  const float* sdf  = (const float*)d_in[2];
  const float* Wf   = (const float*)d_in[3];
  const float* bfv  = (const float*)d_in[4];
  const float* Wsdf = (const float*)d_in[5];
  const float* bsdf = (const float*)d_in[6];
  const int* gt = (const int*)d_in[7];
  float* ws = (float*)d_ws;
  float* out = (float*)d_out;

  k_pool <<<dim3(318, 8), 256, 0, stream>>>(x, feat, sdf, ws);
  k_pass2<<<512, 256, 0, stream>>>(x, feat, sdf, Wf, bfv, Wsdf, bsdf, ws);
  k_pass3<<<512, 256, 0, stream>>>(feat, gt, ws, out);
  k_out  <<<128, 384, 0, stream>>>(ws, out);
}

// Round 5
// 499.752 us; speedup vs baseline: 1.6251x; 1.6251x over previous
//
#include <hip/hip_runtime.h>
#include <hip/hip_bf16.h>

// B=2, DIM=32, CV=HDIM=96, H=W=512, FOLD=8 -> 128 tiles of 64x64, S=4 (P=2), NCLS=16.
// R5: R4's register-spill pipeline reverted (WRITE_SIZE 520MB = scratch traffic).
// pass2 = R3 body + fused k_centers preamble (no prefetch, no launch_bounds min-arg).
// pass3 = R3 body + deterministic fin1 + bounded 12+12 two-batch pipeline
// (next batch in flight across combine/score/MFMA syncs; ~200 VGPR, no spill).

// ---- ws layout (float offsets) ----
#define OFF_POOLX   0          // [128][32][4]
#define OFF_POOLS   16384      // [128][31][4]
#define OFF_CENPF0  32256      // [128][96][4]
#define OFF_NUM1    114688     // [128][96][4]  (zeroed, atomics)
#define OFF_DEN1    163840     // [128][4]      (zeroed, atomics)
#define OFF_OUTNUM  214016     // [128][96][4]  (zeroed, atomics)
#define OFF_OUTDEN  263168     // [128][4]      (zeroed, atomics)
#define OFF_LABELS  263680     // [128][4][16]  (zeroed, atomics)
#define OFF_G       271872     // [128][4096][4] f32 interleaved (px-major, s-minor)
#define ZERO_BASE   OFF_NUM1
#define ZERO_LEN    157184     // floats: NUM1..LABELS end

// ---- d_out layout (float elements) ----
#define OUT_CF 0        // center_feat [2][256][96]
#define OUT_LB 49152    // labels      [2][16][256]
#define OUT_SP 57344    // spix_map    [2][512][512]

#define PL 262144       // plane size (floats)

typedef float f32x4 __attribute__((ext_vector_type(4)));
typedef short bf16x8 __attribute__((ext_vector_type(8)));
typedef unsigned short u16x4 __attribute__((ext_vector_type(4)));

__device__ __forceinline__ unsigned short f2bf(float f) {
  return (unsigned short)(__float_as_uint(f) >> 16);   // truncate; tolerant paths only
}

// K1: block per (plane 0..317, f1 band 0..7): reads 64 rows x 512 cols (128 KB),
// writes 8 tiles x 4 quadrant means. Known-good ~120us reader.
// Also zero-inits the atomic ws regions (replaces hipMemsetAsync dispatch).
__global__ __launch_bounds__(256) void k_pool(const float* __restrict__ x,
    const float* __restrict__ feat, const float* __restrict__ sdf,
    float* __restrict__ ws) {
  int plane = blockIdx.x, f1 = blockIdx.y, tid = threadIdx.x;
  {
    int lb = blockIdx.y * gridDim.x + blockIdx.x;
    if (tid < 64) {
      int zi = lb * 64 + tid;
      if (zi < ZERO_LEN) ws[ZERO_BASE + zi] = 0.f;
    }
  }
  int b = plane / 159, ch = plane % 159;
  const float* src; int c, C, cls;
  if (ch < 32)      { src = x;    C = 32; c = ch;      cls = 0; }
  else if (ch < 63) { src = sdf;  C = 31; c = ch - 32; cls = 1; }
  else              { src = feat; C = 96; c = ch - 63; cls = 2; }
  const float* base = src + ((size_t)(b*C + c)*512 + f1*64)*512;
  int half = tid >> 7, col4 = tid & 127;
  const float* p0 = base + (size_t)half*512 + (size_t)col4*4;  // rows y=2i+half
  f32x4 v[16];
  float acc0 = 0.f, acc1 = 0.f;    // qy=0 / qy=1
  #pragma unroll
  for (int i = 0; i < 16; ++i)
    v[i] = *reinterpret_cast<const f32x4*>(p0 + (size_t)i*1024);
  #pragma unroll
  for (int i = 0; i < 16; ++i) { f32x4 t = v[i]; acc0 += t[0] + t[1] + t[2] + t[3]; }
  #pragma unroll
  for (int i = 0; i < 16; ++i)
    v[i] = *reinterpret_cast<const f32x4*>(p0 + (size_t)(16 + i)*1024);
  #pragma unroll
  for (int i = 0; i < 16; ++i) { f32x4 t = v[i]; acc1 += t[0] + t[1] + t[2] + t[3]; }
  acc0 += __shfl_xor(acc0, 1, 64); acc0 += __shfl_xor(acc0, 2, 64); acc0 += __shfl_xor(acc0, 4, 64);
  acc1 += __shfl_xor(acc1, 1, 64); acc1 += __shfl_xor(acc1, 2, 64); acc1 += __shfl_xor(acc1, 4, 64);
  __shared__ float part[32][2];
  int lane = tid & 63;
  if ((lane & 7) == 0) {
    int f2 = col4 >> 4, qx = (col4 >> 3) & 1;
    part[(f2*2 + qx)*2 + 0][half] = acc0;
    part[(f2*2 + qx)*2 + 1][half] = acc1;
  }
  __syncthreads();
  if (tid < 32) {
    float v2 = (part[tid][0] + part[tid][1]) * (1.f/1024.f);
    int f2 = tid >> 2, qx = (tid >> 1) & 1, qy = tid & 1;
    int tile = b*64 + f1*8 + f2, s = qy*2 + qx;
    float* dst;
    if (cls == 0)      dst = ws + OFF_POOLX  + (tile*32 + c)*4;
    else if (cls == 1) dst = ws + OFF_POOLS  + (tile*31 + c)*4;
    else               dst = ws + OFF_CENPF0 + (tile*96 + c)*4;
    dst[s] = v2;
  }
}

// K3: SSN iter0. 4 WGs/tile x 1024 px, 4 chunks of 256 px. R3 load structure
// (8-wide rounds, consumed inline -> no spill). Centers computed per-block in
// the preamble (scratch overlaid on s_pfT; deterministic gconst/norm0).
__global__ __launch_bounds__(256) void k_pass2(const float* __restrict__ x,
    const float* __restrict__ feat, const float* __restrict__ sdf,
    const float* __restrict__ Wf, const float* __restrict__ bfv,
    const float* __restrict__ Wsdf, const float* __restrict__ bsdf,
    float* __restrict__ ws) {
  int wg = blockIdx.x, tile = wg >> 2, seg = wg & 3, tid = threadIdx.x;
  int b = tile >> 6, tl = tile & 63, f1 = tl >> 3, f2 = tl & 7;
  __shared__ float s_cpf0[384];
  __shared__ float s_udf[128];
  __shared__ float s_usf[124];
  __shared__ float s_gc[4], s_n0[4];
  __shared__ __align__(16) unsigned short s_pfT[96][264];  // [c][px] bf16
  __shared__ __align__(16) unsigned short s_aT[16][264];   // [n][px] bf16; rows 4..15 zero
  __shared__ __align__(16) float s_part[2][8][260];        // [pair][d0-3,p0-3][px]
  // ---- fused k_centers preamble; scratch overlays s_pfT storage ----
  float* scr  = reinterpret_cast<float*>(&s_pfT[0][0]);
  float* c_px = scr;          // [128]
  float* c_ps = scr + 128;    // [124]
  float* c_df = scr + 256;    // [384]
  float* c_sf = scr + 640;    // [384]
  for (int i = tid; i < 384; i += 256) s_cpf0[i] = ws[OFF_CENPF0 + tile*384 + i];
  if (tid < 128) c_px[tid] = ws[OFF_POOLX + tile*128 + tid];
  if (tid < 124) c_ps[tid] = ws[OFF_POOLS + tile*124 + tid];
  __syncthreads();
  for (int i = tid; i < 384; i += 256) {
    int c = i % 96, s = i / 96;
    float a = bfv[c];
    for (int k = 0; k < 32; ++k) a += Wf[c*32 + k] * c_px[k*4 + s];
    c_df[c*4 + s] = a;
    float a2 = bsdf[c];
    for (int k = 0; k < 31; ++k) a2 += Wsdf[c*31 + k] * c_ps[k*4 + s];
    c_sf[c*4 + s] = a2;
  }
  __syncthreads();
  if (tid < 128) {
    int s2 = tid >> 5, k = tid & 31;
    float u = 0.f;
    for (int c2 = 0; c2 < 96; ++c2) u += Wf[c2*32 + k] * c_df[c2*4 + s2];
    s_udf[tid] = u;
  } else if (tid < 252) {
    int t2 = tid - 128, s2 = t2 / 31, k = t2 % 31;
    float u = 0.f;
    for (int c2 = 0; c2 < 96; ++c2) u += Wsdf[c2*31 + k] * c_sf[c2*4 + s2];
    s_usf[t2] = u;
  } else {
    int s = tid - 252;           // deterministic serial gconst/norm0
    float g = 0.f, n = 0.f;
    for (int c = 0; c < 96; ++c) {
      float a = c_df[c*4 + s], a2 = c_sf[c*4 + s];
      g += 2.f*(bfv[c]*a + bsdf[c]*a2) - (a*a + a2*a2);
      float cp = s_cpf0[c*4 + s];
      n += cp*cp;
    }
    s_gc[s] = g; s_n0[s] = n;
  }
  for (int i = tid; i < 16*264; i += 256) (&s_aT[0][0])[i] = 0;
  __syncthreads();   // scratch region free; s_pfT usable from here
  int lane = tid & 63, wave = tid >> 6;
  int mrow = lane & 15, quad = lane >> 4;
  int q4 = lane * 4;
  f32x4 zero4 = {0.f, 0.f, 0.f, 0.f};
  f32x4 accC[6] = {zero4, zero4, zero4, zero4, zero4, zero4};
  float dden[4] = {0.f, 0.f, 0.f, 0.f};
  const float* xb = x   + (size_t)(b*32)*PL;
  const float* sb = sdf + (size_t)(b*31)*PL;
  const float* fb = feat+ (size_t)(b*96)*PL;
  for (int chunk = 0; chunk < 4; ++chunk) {
    int pq = seg*1024 + chunk*256 + q4;
    int goq = (f1*64 + (pq >> 6))*512 + f2*64 + (pq & 63);
    f32x4 dpd[4] = {zero4, zero4, zero4, zero4};
    f32x4 dpp[4] = {zero4, zero4, zero4, zero4};
    f32x4 vv[8];
    // x: channels wave+4i
    #pragma unroll
    for (int i = 0; i < 8; ++i)
      vv[i] = *reinterpret_cast<const f32x4*>(xb + (size_t)(wave + 4*i)*PL + goq);
    #pragma unroll
    for (int i = 0; i < 8; ++i) {
      int ch = wave + 4*i;
      #pragma unroll
      for (int s = 0; s < 4; ++s) dpd[s] += vv[i] * s_udf[s*32 + ch];
    }
    // sdf: channels wave+4i (<31)
    #pragma unroll
    for (int i = 0; i < 8; ++i)
      if (wave + 4*i < 31)
        vv[i] = *reinterpret_cast<const f32x4*>(sb + (size_t)(wave + 4*i)*PL + goq);
    #pragma unroll
    for (int i = 0; i < 8; ++i) {
      int ch = wave + 4*i;
      if (ch < 31) {
        #pragma unroll
        for (int s = 0; s < 4; ++s) dpd[s] += vv[i] * s_usf[s*31 + ch];
      }
    }
    // feat: channels wave+4i, 3 rounds of 8
    #pragma unroll
    for (int r = 0; r < 3; ++r) {
      #pragma unroll
      for (int i = 0; i < 8; ++i)
        vv[i] = *reinterpret_cast<const f32x4*>(fb + (size_t)(wave + 4*(r*8 + i))*PL + goq);
      #pragma unroll
      for (int i = 0; i < 8; ++i) {
        int ch = wave + 4*(r*8 + i);
        u16x4 uu = { f2bf(vv[i][0]), f2bf(vv[i][1]), f2bf(vv[i][2]), f2bf(vv[i][3]) };
        *reinterpret_cast<u16x4*>(&s_pfT[ch][q4]) = uu;
        #pragma unroll
        for (int s = 0; s < 4; ++s) dpp[s] += vv[i] * s_cpf0[ch*4 + s];
      }
    }
    // combine partials: waves 2,3 store; waves 0,1 add
    if (wave >= 2) {
      #pragma unroll
      for (int s = 0; s < 4; ++s) {
        *reinterpret_cast<f32x4*>(&s_part[wave-2][s][q4]) = dpd[s];
        *reinterpret_cast<f32x4*>(&s_part[wave-2][4+s][q4]) = dpp[s];
      }
    }
    __syncthreads();
    if (wave < 2) {
      #pragma unroll
      for (int s = 0; s < 4; ++s) {
        f32x4 t = *reinterpret_cast<f32x4*>(&s_part[wave][s][q4]);
        t += dpd[s];
        *reinterpret_cast<f32x4*>(&s_part[wave][s][q4]) = t;
        f32x4 t2 = *reinterpret_cast<f32x4*>(&s_part[wave][4+s][q4]);
        t2 += dpp[s];
        *reinterpret_cast<f32x4*>(&s_part[wave][4+s][q4]) = t2;
      }
    }
    __syncthreads();
    // score phase: px = tid
    float d0 = s_part[0][0][tid] + s_part[1][0][tid];
    float d1 = s_part[0][1][tid] + s_part[1][1][tid];
    float d2 = s_part[0][2][tid] + s_part[1][2][tid];
    float d3 = s_part[0][3][tid] + s_part[1][3][tid];
    float p0 = s_part[0][4][tid] + s_part[1][4][tid];
    float p1 = s_part[0][5][tid] + s_part[1][5][tid];
    float p2 = s_part[0][6][tid] + s_part[1][6][tid];
    float p3 = s_part[0][7][tid] + s_part[1][7][tid];
    float g0 = 2.f*d0 + s_gc[0], g1 = 2.f*d1 + s_gc[1];
    float g2 = 2.f*d2 + s_gc[2], g3 = 2.f*d3 + s_gc[3];
    int p = seg*1024 + chunk*256 + tid;
    {
      f32x4 gv = {g0, g1, g2, g3};
      *reinterpret_cast<f32x4*>(ws + OFF_G + ((size_t)tile << 14) + (size_t)p*4) = gv;
    }
    float sc0 = g0 + 2.f*p0 - s_n0[0];
    float sc1 = g1 + 2.f*p1 - s_n0[1];
    float sc2 = g2 + 2.f*p2 - s_n0[2];
    float sc3 = g3 + 2.f*p3 - s_n0[3];
    float m = fmaxf(fmaxf(sc0, sc1), fmaxf(sc2, sc3));
    float e0 = expf(sc0 - m), e1 = expf(sc1 - m), e2 = expf(sc2 - m), e3 = expf(sc3 - m);
    float inv = 1.f / (e0 + e1 + e2 + e3);
    float a0 = e0*inv, a1 = e1*inv, a2 = e2*inv, a3 = e3*inv;
    s_aT[0][tid] = f2bf(a0); s_aT[1][tid] = f2bf(a1);
    s_aT[2][tid] = f2bf(a2); s_aT[3][tid] = f2bf(a3);
    dden[0] += a0; dden[1] += a1; dden[2] += a2; dden[3] += a3;
    __syncthreads();
    #pragma unroll
    for (int kk = 0; kk < 2; ++kk) {
      int k0 = (wave*2 + kk)*32 + quad*8;
      bf16x8 bfrag = *reinterpret_cast<const bf16x8*>(&s_aT[mrow][k0]);
      #pragma unroll
      for (int mt = 0; mt < 6; ++mt) {
        bf16x8 afrag = *reinterpret_cast<const bf16x8*>(&s_pfT[mt*16 + mrow][k0]);
        accC[mt] = __builtin_amdgcn_mfma_f32_16x16x32_bf16(afrag, bfrag, accC[mt], 0, 0, 0);
      }
    }
    __syncthreads();
  }
  if (mrow < 4) {     // C/D: col=lane&15 (=s), row=quad*4+reg (=c within tile)
    #pragma unroll
    for (int mt = 0; mt < 6; ++mt)
      #pragma unroll
      for (int r = 0; r < 4; ++r) {
        int c = mt*16 + quad*4 + r;
        atomicAdd(&ws[OFF_NUM1 + (tile*96 + c)*4 + mrow], accC[mt][r]);
      }
  }
  for (int m2 = 1; m2 < 64; m2 <<= 1) {
    dden[0] += __shfl_xor(dden[0], m2, 64); dden[1] += __shfl_xor(dden[1], m2, 64);
    dden[2] += __shfl_xor(dden[2], m2, 64); dden[3] += __shfl_xor(dden[3], m2, 64);
  }
  if (lane == 0) {
    atomicAdd(&ws[OFF_DEN1 + tile*4 + 0], dden[0]);
    atomicAdd(&ws[OFF_DEN1 + tile*4 + 1], dden[1]);
    atomicAdd(&ws[OFF_DEN1 + tile*4 + 2], dden[2]);
    atomicAdd(&ws[OFF_DEN1 + tile*4 + 3], dden[3]);
  }
}

// K5: SSN iter1. fin1 fused (deterministic). Bounded 12+12 two-batch pipeline:
// batch B issues before A is consumed; next chunk's batch A (+g,gt) issues
// before the combine/score/MFMA syncs, staying in flight across them.
__global__ __launch_bounds__(256) void k_pass3(const float* __restrict__ feat,
    const int* __restrict__ gt, float* __restrict__ ws, float* __restrict__ out) {
  int wg = blockIdx.x, tile = wg >> 2, seg = wg & 3, tid = threadIdx.x;
  int b = tile >> 6, tl = tile & 63, f1 = tl >> 3, f2 = tl & 7;
  __shared__ float s_cpf1[384];
  __shared__ float s_n1[4];
  __shared__ __align__(16) unsigned short s_pfT[96][264];
  __shared__ __align__(16) unsigned short s_aT[16][264];
  __shared__ __align__(16) float s_part[2][4][260];
  __shared__ float s_hist[64];
  if (tid < 64) s_hist[tid] = 0.f;
  for (int i = tid; i < 16*264; i += 256) (&s_aT[0][0])[i] = 0;
  // fused fin1: cen_pf1 = NUM1/(DEN1+eps); then deterministic norm1
  for (int i = tid; i < 384; i += 256) {
    float den = ws[OFF_DEN1 + tile*4 + (i & 3)];
    s_cpf1[i] = ws[OFF_NUM1 + tile*384 + i] / (den + 1e-16f);
  }
  __syncthreads();
  if (tid < 4) {
    float n = 0.f;
    for (int c = 0; c < 96; ++c) { float v = s_cpf1[c*4 + tid]; n += v*v; }
    s_n1[tid] = n;
  }
  __syncthreads();
  int lane = tid & 63, wave = tid >> 6;
  int mrow = lane & 15, quad = lane >> 4;
  int q4 = lane * 4;
  f32x4 zero4 = {0.f, 0.f, 0.f, 0.f};
  f32x4 accC[6] = {zero4, zero4, zero4, zero4, zero4, zero4};
  float oden[4] = {0.f, 0.f, 0.f, 0.f};
  const float* fb = feat + (size_t)(b*96)*PL;
  f32x4 fvA[12], fvB[12];
  f32x4 gfut; int gtfut;
  // prefetch chunk 0: batch A (i=0..11) + g + gt
  {
    int pq = seg*1024 + q4;
    int goq = (f1*64 + (pq >> 6))*512 + f2*64 + (pq & 63);
    #pragma unroll
    for (int i = 0; i < 12; ++i)
      fvA[i] = *reinterpret_cast<const f32x4*>(fb + (size_t)(wave + 4*i)*PL + goq);
    int p0i = seg*1024 + tid;
    gfut = *reinterpret_cast<const f32x4*>(ws + OFF_G + ((size_t)tile << 14) + (size_t)p0i*4);
    gtfut = gt[b*262144 + (f1*64 + (p0i >> 6))*512 + f2*64 + (p0i & 63)];
  }
  for (int chunk = 0; chunk < 4; ++chunk) {
    int pq = seg*1024 + chunk*256 + q4;
    int goq = (f1*64 + (pq >> 6))*512 + f2*64 + (pq & 63);
    int pq1 = seg*1024 + (chunk+1)*256 + q4;
    int goq1 = (f1*64 + (pq1 >> 6))*512 + f2*64 + (pq1 & 63);
    f32x4 gcur = gfut; int gtcur = gtfut;
    f32x4 dpp[4] = {zero4, zero4, zero4, zero4};
    // issue batch B (this chunk, i=12..23)
    #pragma unroll
    for (int i = 0; i < 12; ++i)
      fvB[i] = *reinterpret_cast<const f32x4*>(fb + (size_t)(wave + 4*(12 + i))*PL + goq);
    // consume batch A (ch order i=0..11 preserved)
    #pragma unroll
    for (int i = 0; i < 12; ++i) {
      int ch = wave + 4*i;
      u16x4 uu = { f2bf(fvA[i][0]), f2bf(fvA[i][1]), f2bf(fvA[i][2]), f2bf(fvA[i][3]) };
      *reinterpret_cast<u16x4*>(&s_pfT[ch][q4]) = uu;
      #pragma unroll
      for (int s = 0; s < 4; ++s) dpp[s] += fvA[i] * s_cpf1[ch*4 + s];
    }
    // issue next chunk's batch A + g + gt (in flight across syncs)
    if (chunk < 3) {
      #pragma unroll
      for (int i = 0; i < 12; ++i)
        fvA[i] = *reinterpret_cast<const f32x4*>(fb + (size_t)(wave + 4*i)*PL + goq1);
      int p1i = seg*1024 + (chunk+1)*256 + tid;
      gfut = *reinterpret_cast<const f32x4*>(ws + OFF_G + ((size_t)tile << 14) + (size_t)p1i*4);
      gtfut = gt[b*262144 + (f1*64 + (p1i >> 6))*512 + f2*64 + (p1i & 63)];
    }
    // consume batch B (ch order i=12..23 preserved)
    #pragma unroll
    for (int i = 0; i < 12; ++i) {
      int ch = wave + 4*(12 + i);
      u16x4 uu = { f2bf(fvB[i][0]), f2bf(fvB[i][1]), f2bf(fvB[i][2]), f2bf(fvB[i][3]) };
      *reinterpret_cast<u16x4*>(&s_pfT[ch][q4]) = uu;
      #pragma unroll
      for (int s = 0; s < 4; ++s) dpp[s] += fvB[i] * s_cpf1[ch*4 + s];
    }
    // combine partials: waves 2,3 store; waves 0,1 add
    if (wave >= 2) {
      #pragma unroll
      for (int s = 0; s < 4; ++s)
        *reinterpret_cast<f32x4*>(&s_part[wave-2][s][q4]) = dpp[s];
    }
    __syncthreads();
    if (wave < 2) {
      #pragma unroll
      for (int s = 0; s < 4; ++s) {
        f32x4 t = *reinterpret_cast<f32x4*>(&s_part[wave][s][q4]);
        t += dpp[s];
        *reinterpret_cast<f32x4*>(&s_part[wave][s][q4]) = t;
      }
    }
    __syncthreads();
    // score phase: px = tid
    int p = seg*1024 + chunk*256 + tid;
    int go = (f1*64 + (p >> 6))*512 + f2*64 + (p & 63);
    float p0 = s_part[0][0][tid] + s_part[1][0][tid];
    float p1 = s_part[0][1][tid] + s_part[1][1][tid];
    float p2 = s_part[0][2][tid] + s_part[1][2][tid];
    float p3 = s_part[0][3][tid] + s_part[1][3][tid];
    float sc0 = gcur[0] + 2.f*p0 - s_n1[0];
    float sc1 = gcur[1] + 2.f*p1 - s_n1[1];
    float sc2 = gcur[2] + 2.f*p2 - s_n1[2];
    float sc3 = gcur[3] + 2.f*p3 - s_n1[3];
    int ss = 0; float best = sc0;
    if (sc1 > best) { best = sc1; ss = 1; }
    if (sc2 > best) { best = sc2; ss = 2; }
    if (sc3 > best) { best = sc3; ss = 3; }
    float se = expf(sc0-best) + expf(sc1-best) + expf(sc2-best) + expf(sc3-best);
    float sim = 1.f / se;
    unsigned short sb = f2bf(sim);
    s_aT[0][tid] = (ss == 0) ? sb : (unsigned short)0;
    s_aT[1][tid] = (ss == 1) ? sb : (unsigned short)0;
    s_aT[2][tid] = (ss == 2) ? sb : (unsigned short)0;
    s_aT[3][tid] = (ss == 3) ? sb : (unsigned short)0;
    oden[ss] += sim;
    atomicAdd(&s_hist[ss*16 + gtcur], 1.f);
    out[OUT_SP + b*262144 + go] = (float)(tl*4 + ss);
    __syncthreads();
    #pragma unroll
    for (int kk = 0; kk < 2; ++kk) {
      int k0 = (wave*2 + kk)*32 + quad*8;
      bf16x8 bfrag = *reinterpret_cast<const bf16x8*>(&s_aT[mrow][k0]);
      #pragma unroll
      for (int mt = 0; mt < 6; ++mt) {
        bf16x8 afrag = *reinterpret_cast<const bf16x8*>(&s_pfT[mt*16 + mrow][k0]);
        accC[mt] = __builtin_amdgcn_mfma_f32_16x16x32_bf16(afrag, bfrag, accC[mt], 0, 0, 0);
      }
    }
    __syncthreads();
  }
  if (mrow < 4) {
    #pragma unroll
    for (int mt = 0; mt < 6; ++mt)
      #pragma unroll
      for (int r = 0; r < 4; ++r) {
        int c = mt*16 + quad*4 + r;
        atomicAdd(&ws[OFF_OUTNUM + (tile*96 + c)*4 + mrow], accC[mt][r]);
      }
  }
  for (int m2 = 1; m2 < 64; m2 <<= 1) {
    oden[0] += __shfl_xor(oden[0], m2, 64); oden[1] += __shfl_xor(oden[1], m2, 64);
    oden[2] += __shfl_xor(oden[2], m2, 64); oden[3] += __shfl_xor(oden[3], m2, 64);
  }
  if (lane == 0) {
    atomicAdd(&ws[OFF_OUTDEN + tile*4 + 0], oden[0]);
    atomicAdd(&ws[OFF_OUTDEN + tile*4 + 1], oden[1]);
    atomicAdd(&ws[OFF_OUTDEN + tile*4 + 2], oden[2]);
    atomicAdd(&ws[OFF_OUTDEN + tile*4 + 3], oden[3]);
  }
  if (tid < 64) atomicAdd(&ws[OFF_LABELS + tile*64 + tid], s_hist[tid]);
}

// K6: epilogue -> center_feat and labels
__global__ __launch_bounds__(384) void k_out(const float* __restrict__ ws,
                                             float* __restrict__ out) {
  int tile = blockIdx.x, tid = threadIdx.x;
  int b = tile >> 6, tl = tile & 63;
  int c = tid % 96, s = tid / 96;
  float od = ws[OFF_OUTDEN + tile*4 + s];
  float v = (ws[OFF_OUTNUM + (tile*96 + c)*4 + s] + ws[OFF_CENPF0 + (tile*96 + c)*4 + s]) / (od + 1.f);
  out[OUT_CF + (size_t)(b*256 + tl*4 + s)*96 + c] = v;
  if (tid < 64) {
    int s2 = tid >> 4, cls = tid & 15;
    float cnt = ws[OFF_LABELS + tile*64 + tid];
    out[OUT_LB + (b*16 + cls)*256 + tl*4 + s2] = cnt;
  }
}

extern "C" void kernel_launch(void* const* d_in, const int* in_sizes, int n_in,
                              void* d_out, int out_size, void* d_ws, size_t ws_size,
                              hipStream_t stream) {
  const float* x    = (const float*)d_in[0];
  const float* feat = (const float*)d_in[1];
  const float* sdf  = (const float*)d_in[2];
  const float* Wf   = (const float*)d_in[3];
  const float* bfv  = (const float*)d_in[4];
  const float* Wsdf = (const float*)d_in[5];
  const float* bsdf = (const float*)d_in[6];
  const int* gt = (const int*)d_in[7];
  float* ws = (float*)d_ws;
  float* out = (float*)d_out;

  k_pool <<<dim3(318, 8), 256, 0, stream>>>(x, feat, sdf, ws);
  k_pass2<<<512, 256, 0, stream>>>(x, feat, sdf, Wf, bfv, Wsdf, bsdf, ws);
  k_pass3<<<512, 256, 0, stream>>>(feat, gt, ws, out);
  k_out  <<<128, 384, 0, stream>>>(ws, out);
}